// Round 6
// baseline (5291.678 us; speedup 1.0000x reference)
//
#include <hip/hip_runtime.h>
#include <stdint.h>

// Online Neural CDE, fused persistent kernel — fp32 datapath, two-set pipeline,
// 512-thread blocks. 8 groups x 32 blocks; group = 16 batches, sets A(0-7)/B(8-15).
// Each block holds a 1/32 output-row-slice of the vector-field weights in LDS.
// Cross-block exchange via fine-grained agent-scope (sc1) loads/stores through
// the Infinity Cache; group sync via per-block epoch flags.
// R6: L4 kq1 remap (broadcast-maximal LDS reads, 1 tanh/dot, no k-shfl),
//     precomputed searchsorted table (s_sj), 4-chain FMA ILP in L4.

#define NGRP 8
#define NJ   32
#define NTHR 512
#define STW  276   // dword stride for 256-col tiles (4-dword gap per 64 cols)
#define STY  132   // dword stride for 128-col y tile (gap at col 64)

typedef unsigned long long u64t;

static __device__ __forceinline__ u64t ld_coh8(const u64t* p) {
  return __hip_atomic_load(p, __ATOMIC_RELAXED, __HIP_MEMORY_SCOPE_AGENT);
}
static __device__ __forceinline__ float ld_coh4(const float* p) {
  return __hip_atomic_load(p, __ATOMIC_RELAXED, __HIP_MEMORY_SCOPE_AGENT);
}
static __device__ __forceinline__ void st_coh4(float* p, float v) {
  __hip_atomic_store(p, v, __ATOMIC_RELAXED, __HIP_MEMORY_SCOPE_AGENT);
}

// jax.nn.softplus(x) = max(x,0) + log1p(exp(-|x|))
static __device__ __forceinline__ float sp(float x) {
  return fmaxf(x, 0.f) + log1pf(expf(-fabsf(x)));
}

// np.searchsorted(kn, t, 'right') - 1, clipped to [0, 62]; 64 knots.
static __device__ __forceinline__ int seg_idx(const float* kn, float t) {
  int lo = 0, hi = 64;
  while (lo < hi) { int mid = (lo + hi) >> 1; if (kn[mid] <= t) lo = mid + 1; else hi = mid; }
  int jj = lo - 1;
  return jj < 0 ? 0 : (jj > 62 ? 62 : jj);
}

static __device__ __forceinline__ float dot4(float4 w, float4 a, float acc) {
  acc = fmaf(w.x, a.x, acc);
  acc = fmaf(w.y, a.y, acc);
  acc = fmaf(w.z, a.z, acc);
  return fmaf(w.w, a.w, acc);
}

__global__ void __launch_bounds__(NTHR)
ncde_kernel(const float* __restrict__ ts, const float* __restrict__ tsi,
            const float* __restrict__ obs, const float* __restrict__ tmax,
            const float* __restrict__ i_win, const float* __restrict__ i_bin,
            const float* __restrict__ i_wmid, const float* __restrict__ i_bmid,
            const float* __restrict__ i_wout, const float* __restrict__ i_bout,
            const float* __restrict__ v_win, const float* __restrict__ v_bin,
            const float* __restrict__ v_wmid, const float* __restrict__ v_bmid,
            const float* __restrict__ v_wout, const float* __restrict__ v_bout,
            float* __restrict__ out, uint32_t* __restrict__ ws)
{
  __shared__ __align__(16) float w_l4[64][STW];   // v_wout rows 64j..64j+63
  __shared__ __align__(16) float w_m0[8][STW];    // v_wmid[0] rows 8j..
  __shared__ __align__(16) float w_m1[8][STW];    // v_wmid[1] rows 8j..
  __shared__ __align__(16) float w_l1[8][STY];    // v_win rows 8j..
  __shared__ __align__(16) float s_act[16][STW];  // staged activations (rows 8s..)
  __shared__ __align__(16) float s_y[16][STY];    // staged y input (rows 8s..)
  __shared__ __align__(16) float s_ts[16][64];
  __shared__ __align__(16) float s_kn[16][64];
  __shared__ float s_dx[16][16];
  __shared__ float s_part[8][9];                  // L4 d-half partials [bb][w8]
  __shared__ unsigned char s_sj[16][128];         // searchsorted table per (bb,ti)
  __shared__ float s_dt[16], s_tm[16];
  __shared__ float sb_l1[8], sb_m0[8], sb_m1[8], sb_l4[64];

  const int tid = threadIdx.x;
  const int bid = blockIdx.x;
  const int g = bid & 7;    // group (== XCD under round-robin; perf heuristic only)
  const int j = bid >> 3;   // slice 0..31

  uint32_t* flagA = ws + (size_t)(g * 2 + 0) * 64;
  uint32_t* flagB = ws + (size_t)(g * 2 + 1) * 64;
  float* base = (float*)(ws + 1024) + (size_t)g * 18432;
  float* yw = base;           // [2][16][128]
  float* kw = base + 4096;    // [16][128]
  float* h1 = base + 6144;    // [16][256]
  float* h2 = base + 10240;
  float* h3 = base + 14336;

  // ---------------- load weight slices -> LDS (fp32, gapped cols) ----------
  for (int e2 = tid; e2 < 64 * 64; e2 += NTHR) {   // w_l4: 64 rows x 64 f4
    int r = e2 >> 6, c4 = e2 & 63; int k = 4 * c4;
    float4 v = *(const float4*)(v_wout + (size_t)(64 * j + r) * 256 + k);
    *(float4*)&w_l4[r][k + 4 * (k >> 6)] = v;
  }
  for (int e2 = tid; e2 < 8 * 64; e2 += NTHR) {    // mids: 8 rows x 64 f4 each
    int r = e2 >> 6, c4 = e2 & 63; int k = 4 * c4;
    float4 a = *(const float4*)(v_wmid + (size_t)(8 * j + r) * 256 + k);
    float4 b2 = *(const float4*)(v_wmid + 65536 + (size_t)(8 * j + r) * 256 + k);
    int col = k + 4 * (k >> 6);
    *(float4*)&w_m0[r][col] = a;
    *(float4*)&w_m1[r][col] = b2;
  }
  if (tid < 256) {                                 // w_l1: 8 rows x 32 f4
    int r = tid >> 5, c4 = tid & 31; int k = 4 * c4;
    float4 v = *(const float4*)(v_win + (size_t)(8 * j + r) * 128 + k);
    *(float4*)&w_l1[r][k + 4 * (k >> 6)] = v;
  }
  if (tid < 8) {
    sb_l1[tid] = v_bin[8 * j + tid];
    sb_m0[tid] = v_bmid[8 * j + tid];
    sb_m1[tid] = v_bmid[256 + 8 * j + tid];
  }
  if (tid < 64) sb_l4[tid] = v_bout[64 * j + tid];
  for (int e2 = tid; e2 < 16 * 64; e2 += NTHR) {
    int bb = e2 >> 6, i2 = e2 & 63;
    int b = g * 16 + bb;
    s_ts[bb][i2] = ts[b * 64 + i2];
    s_kn[bb][i2] = tsi[b * 64 + i2];
  }
  if (tid < 16) s_tm[tid] = tmax[g * 16 + tid];
  __syncthreads();

  // -------- precompute searchsorted table: ti = 2l (t_l), 2l+1 (mid) -------
  for (int e2 = tid; e2 < 2048; e2 += NTHR) {
    int bb = e2 >> 7, ti = e2 & 127;
    if (ti < 127) {
      int li = ti >> 1;
      float te = (ti & 1) ? fmaf(0.5f, s_ts[bb][li + 1] - s_ts[bb][li], s_ts[bb][li])
                          : s_ts[bb][li];
      s_sj[bb][ti] = (unsigned char)seg_idx(&s_kn[bb][0], te);
    }
  }
  __syncthreads();

  uint32_t epA = 0, epB = 0;

  auto signal = [&](uint32_t* flg, uint32_t ep) {
    asm volatile("s_waitcnt vmcnt(0)" ::: "memory");
    __syncthreads();
    if (tid == 0)
      __hip_atomic_store(flg + j, ep, __ATOMIC_RELAXED, __HIP_MEMORY_SCOPE_AGENT);
  };
  auto wait = [&](uint32_t* flg, uint32_t ep) {
    if (tid < 64) {
      uint32_t it = 0;
      for (;;) {
        uint32_t f = __hip_atomic_load(flg + (tid & 31), __ATOMIC_RELAXED,
                                       __HIP_MEMORY_SCOPE_AGENT);
        if (__all((int)(f >= ep))) break;
        __builtin_amdgcn_s_sleep(1);
        if (++it > (1u << 20)) break;  // failsafe: no hang
      }
    }
    __syncthreads();
  };

  // stage 8 batches x 256 acts (sc1) -> gapped LDS rows 8s..8s+7
  auto stageH = [&](int s, const float* hsrc) {
    const u64t* hp = (const u64t*)(hsrc + s * 2048);
#pragma unroll
    for (int it = 0; it < 2; ++it) {
      int e2 = tid + it * NTHR;
      int bb = e2 >> 7, c2 = e2 & 127;
      u64t v = ld_coh8(hp + bb * 128 + c2);
      int k = 2 * c2;
      *(u64t*)&s_act[8 * s + bb][k + 4 * (k >> 6)] = v;
    }
    __syncthreads();
  };

  // L1: 128-in (s_y) -> 8-row slice, softplus. lanes: bb8(0-2) kq8(3-5) o8(wave)
  auto L1f = [&](int s) {
    int bb = tid & 7, kq = (tid >> 3) & 7, o = tid >> 6;
    int off = 16 * kq + 4 * (kq >> 2);
    float acc = 0.f;
    const float* wr = &w_l1[o][off];
    const float* ar = &s_y[8 * s + bb][off];
#pragma unroll
    for (int c = 0; c < 4; ++c)
      acc = dot4(*(const float4*)(wr + 4 * c), *(const float4*)(ar + 4 * c), acc);
    acc += __shfl_xor(acc, 8);
    acc += __shfl_xor(acc, 16);
    acc += __shfl_xor(acc, 32);
    if (kq == 0) st_coh4(&h1[s * 2048 + bb * 256 + 8 * j + o], sp(acc + sb_l1[o]));
  };

  // mid: 256-in (s_act) -> 8-row slice, softplus. lanes: bb8 kq8 o8(wave)
  auto midf = [&](int s, const float (*W)[STW], const float* bias, float* hdst) {
    int bb = tid & 7, kq = (tid >> 3) & 7, o = tid >> 6;
    int off = 32 * kq + 4 * (kq >> 1);
    float acc = 0.f;
    const float* wr = &W[o][off];
    const float* ar = &s_act[8 * s + bb][off];
#pragma unroll
    for (int c = 0; c < 8; ++c)
      acc = dot4(*(const float4*)(wr + 4 * c), *(const float4*)(ar + 4 * c), acc);
    acc += __shfl_xor(acc, 8);
    acc += __shfl_xor(acc, 16);
    acc += __shfl_xor(acc, 32);
    if (kq == 0) st_coh4(&hdst[s * 2048 + bb * 256 + 8 * j + o], sp(acc + bias[o]));
  };

  // stage y_in = y (+ c*dt*k) for one set (8 batches x 64 u64)
  auto stageY = [&](int s, int cur, int e) {
    const u64t* ywc = (const u64t*)(yw + cur * 2048 + s * 1024);
    const u64t* kwp = (const u64t*)(kw + s * 1024);
    int bb = tid >> 6, c2 = tid & 63;
    float2 yv = __builtin_bit_cast(float2, ld_coh8(ywc + bb * 64 + c2));
    if (e > 0) {
      float cd = ((e == 3) ? 1.f : 0.5f) * s_dt[8 * s + bb];
      float2 kv = __builtin_bit_cast(float2, ld_coh8(kwp + bb * 64 + c2));
      yv.x = fmaf(cd, kv.x, yv.x);
      yv.y = fmaf(cd, kv.y, yv.y);
    }
    int i2 = 2 * c2;
    *(float2*)&s_y[8 * s + bb][i2 + 4 * (i2 >> 6)] = yv;
  };

  // L4: one thread = one full (row,bb) dot. lanes: bb(0-2) rlo(3-5); wave: rhi.
  // w-reads broadcast over bb (8-way), a-reads broadcast over rlo (8-way).
  auto L4f = [&](int s, int e, int cur, int nxt, int l, float& ka) {
    const int bb = tid & 7, rlo = (tid >> 3) & 7, w8 = tid >> 6;
    const int r = (w8 << 3) | rlo;                 // slice row 0..63
    const float* wr = &w_l4[r][0];
    const float* ar = &s_act[8 * s + bb][0];
    float acc[4] = {0.f, 0.f, 0.f, 0.f};
#pragma unroll
    for (int c4 = 0; c4 < 64; ++c4) {
      int off = 4 * c4 + 4 * (c4 >> 4);
      acc[c4 & 3] = dot4(*(const float4*)(wr + off), *(const float4*)(ar + off),
                         acc[c4 & 3]);
    }
    float z = (acc[0] + acc[1]) + (acc[2] + acc[3]) + sb_l4[r];
    float v = tanhf(z) * s_dx[8 * s + bb][r & 15];
    v += __shfl_xor(v, 8);                         // reduce over rlo (d within half)
    v += __shfl_xor(v, 16);
    v += __shfl_xor(v, 32);
    if (rlo == 0) s_part[bb][w8] = v;              // w8 = hl*2 + dhalf
    __syncthreads();
    if (tid < 32) {
      int bbw = tid & 7, hl = tid >> 3;
      float kv = s_part[bbw][2 * hl] + s_part[bbw][2 * hl + 1];
      int bbg = 8 * s + bbw;
      int hg = 4 * j + hl;
      st_coh4(&kw[bbg * 128 + hg], kv);
      if (e == 0) ka = kv;
      else ka = fmaf((e == 3) ? 1.f : 2.f, kv, ka);
      if (e == 3) {
        float dt = s_dt[bbg];
        float yn = ld_coh4(&yw[cur * 2048 + bbg * 128 + hg]) + dt * (1.f / 6.f) * ka;
        st_coh4(&yw[nxt * 2048 + bbg * 128 + hg], yn);
        int b = g * 16 + bbg;
        out[(size_t)b * 8192 + (size_t)(l + 1) * 128 + hg] =
            (s_ts[bbg][l + 1] <= s_tm[bbg]) ? yn : -99.f;
      }
    }
  };

  // ---------------- init MLP: y0 = MLP_i(x0), weights from global ----------
  if (tid < 256) {
    int bb = tid >> 4, d = tid & 15;
    float t0 = s_ts[bb][0];
    int sj = seg_idx(&s_kn[bb][0], t0);
    float k0 = s_kn[bb][sj], k1 = s_kn[bb][sj + 1];
    float fr = (t0 - k0) / (k1 - k0);
    const float* ob = obs + ((size_t)(g * 16 + bb) * 64 + sj) * 16 + d;
    float o0 = ob[0], o1 = ob[16];
    s_y[bb][d] = fmaf(fr, o1 - o0, o0);
  }
  __syncthreads();
  if (tid < 128) {  // L1i: 16-in, 8-row slice
    int bb = tid & 15, o = tid >> 4;
    float acc = i_bin[8 * j + o];
    const float* wr = i_win + (size_t)(8 * j + o) * 16;
#pragma unroll
    for (int i2 = 0; i2 < 16; ++i2) acc = fmaf(wr[i2], s_y[bb][i2], acc);
    st_coh4(&h1[bb * 256 + 8 * j + o], sp(acc));
  }
  ++epA; signal(flagA, epA); wait(flagA, epA);
  for (int layer = 0; layer < 2; ++layer) {  // mid-i: bb16 kq4 o8 (512 thr)
    stageH(0, layer == 0 ? h1 : h2);
    stageH(1, layer == 0 ? h1 : h2);
    int bb = tid & 15, kq = (tid >> 4) & 3, o = tid >> 6;
    float acc = 0.f;
    const float* wr = i_wmid + (size_t)layer * 65536 + (size_t)(8 * j + o) * 256 + kq * 64;
    const float* ar = &s_act[bb][68 * kq];
#pragma unroll
    for (int c = 0; c < 16; ++c)
      acc = dot4(*(const float4*)(wr + 4 * c), *(const float4*)(ar + 4 * c), acc);
    acc += __shfl_xor(acc, 16);
    acc += __shfl_xor(acc, 32);
    if (kq == 0) {
      float* hdst = (layer == 0 ? h2 : h3);
      st_coh4(&hdst[bb * 256 + 8 * j + o], sp(acc + i_bmid[layer * 256 + 8 * j + o]));
    }
    ++epA; signal(flagA, epA); wait(flagA, epA);
  }
  {  // L4i: 4-row slice of 128-wide y0, identity; commit y0 + out row 0
    stageH(0, h3);
    stageH(1, h3);
    if (tid < 256) {
      int bb = tid & 15, kq4 = (tid >> 4) & 3, rl = tid >> 6;
      float acc = 0.f;
      const float* wr = i_wout + (size_t)(4 * j + rl) * 256 + kq4 * 64;
      const float* ar = &s_act[bb][kq4 * 68];
#pragma unroll
      for (int c = 0; c < 16; ++c)
        acc = dot4(*(const float4*)(wr + 4 * c), *(const float4*)(ar + 4 * c), acc);
      acc += __shfl_xor(acc, 16);
      acc += __shfl_xor(acc, 32);
      if (kq4 == 0) {
        int hg = 4 * j + rl;
        float y0 = acc + i_bout[hg];
        st_coh4(&yw[bb * 128 + hg], y0);
        int b = g * 16 + bb;
        out[(size_t)b * 8192 + hg] = (s_ts[bb][0] <= s_tm[bb]) ? y0 : -99.f;
      }
    }
  }
  ++epA; signal(flagA, epA);

  // ---------------- RK4 over 63 intervals, two-set pipeline ----------------
  float kaA = 0.f, kaB = 0.f;

#pragma unroll 1
  for (int l = 0; l < 63; ++l) {
    const int cur = l & 1, nxt = cur ^ 1;
    if (tid < 16) s_dt[tid] = s_ts[tid][l + 1] - s_ts[tid][l];
#pragma unroll 1
    for (int e = 0; e < 4; ++e) {
      wait(flagA, epA);                        // prev A4
      if (tid < 256) {  // prologue: dx(t_e) via precomputed seg table
        int bb = tid >> 4, d = tid & 15;
        int ti = 2 * l + ((e == 0) ? 0 : ((e == 3) ? 2 : 1));
        int sj = s_sj[bb][ti];
        const float* ob = obs + ((size_t)(g * 16 + bb) * 64 + sj) * 16 + d;
        s_dx[bb][d] = (ob[16] - ob[0]) / (s_kn[bb][sj + 1] - s_kn[bb][sj]);
      }
      stageY(0, cur, e);
      __syncthreads();
      L1f(0);
      ++epA; signal(flagA, epA);               // A1

      wait(flagB, epB);                        // prev B4
      stageY(1, cur, e);
      __syncthreads();
      L1f(1);
      ++epB; signal(flagB, epB);               // B1

      wait(flagA, epA);                        // A1
      stageH(0, h1); midf(0, w_m0, sb_m0, h2);
      ++epA; signal(flagA, epA);               // A2

      wait(flagB, epB);                        // B1
      stageH(1, h1); midf(1, w_m0, sb_m0, h2);
      ++epB; signal(flagB, epB);               // B2

      wait(flagA, epA);                        // A2
      stageH(0, h2); midf(0, w_m1, sb_m1, h3);
      ++epA; signal(flagA, epA);               // A3

      wait(flagB, epB);                        // B2
      stageH(1, h2); midf(1, w_m1, sb_m1, h3);
      ++epB; signal(flagB, epB);               // B3

      wait(flagA, epA);                        // A3
      stageH(0, h3); L4f(0, e, cur, nxt, l, kaA);
      ++epA; signal(flagA, epA);               // A4

      wait(flagB, epB);                        // B3
      stageH(1, h3); L4f(1, e, cur, nxt, l, kaB);
      ++epB; signal(flagB, epB);               // B4
    }
  }
}

extern "C" void kernel_launch(void* const* d_in, const int* in_sizes, int n_in,
                              void* d_out, int out_size, void* d_ws, size_t ws_size,
                              hipStream_t stream) {
  const float* ts     = (const float*)d_in[0];
  const float* tsi    = (const float*)d_in[1];
  const float* obs    = (const float*)d_in[2];
  const float* tmaxp  = (const float*)d_in[3];
  const float* i_win  = (const float*)d_in[4];
  const float* i_bin  = (const float*)d_in[5];
  const float* i_wmid = (const float*)d_in[6];
  const float* i_bmid = (const float*)d_in[7];
  const float* i_wout = (const float*)d_in[8];
  const float* i_bout = (const float*)d_in[9];
  const float* v_win  = (const float*)d_in[10];
  const float* v_bin  = (const float*)d_in[11];
  const float* v_wmid = (const float*)d_in[12];
  const float* v_bmid = (const float*)d_in[13];
  const float* v_wout = (const float*)d_in[14];
  const float* v_bout = (const float*)d_in[15];

  // zero the epoch flags (first 4KB of ws) each launch (graph-capture safe)
  (void)hipMemsetAsync(d_ws, 0, 4096, stream);

  ncde_kernel<<<dim3(NGRP * NJ), dim3(NTHR), 0, stream>>>(
      ts, tsi, obs, tmaxp,
      i_win, i_bin, i_wmid, i_bmid, i_wout, i_bout,
      v_win, v_bin, v_wmid, v_bmid, v_wout, v_bout,
      (float*)d_out, (uint32_t*)d_ws);
}